// Round 5
// baseline (305.902 us; speedup 1.0000x reference)
//
#include <hip/hip_runtime.h>
#include <math.h>

// Problem constants (from reference setup_inputs)
#define CDIM 64
#define CR 16
#define TFR 8
#define NBATCH 16      // NT / T
#define NTOT 128       // NT
#define HWPIX 3136     // 56*56
#define HW4 784        // HWPIX / 4
#define NMEANBLK (NTOT * CDIM)   // 8192

// ---------------------------------------------------------------------------
// Kernel 1: per-(nt, c) spatial mean of x.  grid = 8192 blocks, 256 threads.
// The LAST block to finish (atomic counter) additionally computes
//   gap[nt][k]  = sum_cc sq_w[k,cc] * (xbar[n,0,cc] - xbar[n,t,cc])   (0 for t=0,7)
//   attp1[nt][c] = 1 + sigmoid( sum_k ex_w[c,k]*gap[nt][k] + ex_b[c] )
// entirely in LDS — removes the separate tiny kernel + its launch gap.
// sq_b cancels in the temporal diff (verified R1).
// ---------------------------------------------------------------------------
__global__ __launch_bounds__(256) void mean_att_kernel(
    const float* __restrict__ x,
    const float* __restrict__ sq_w,   // (CR, C) row-major
    const float* __restrict__ ex_w,   // (C, CR) row-major
    const float* __restrict__ ex_b,   // (C,)
    float* xbar,                      // (NT*C) scratch
    float* __restrict__ attp1,        // (NT*C) scratch out
    unsigned int* counter) {
  const int b = blockIdx.x;  // 0 .. 8191  == nt*CDIM + c
  const float4* xp = reinterpret_cast<const float4*>(x + (size_t)b * HWPIX);
  float s = 0.f;
  for (int i = threadIdx.x; i < HW4; i += 256) {
    float4 v = xp[i];
    s += (v.x + v.y) + (v.z + v.w);
  }
  #pragma unroll
  for (int off = 32; off > 0; off >>= 1) s += __shfl_down(s, off, 64);
  __shared__ float wsum[4];
  __shared__ int is_last;
  const int lane = threadIdx.x & 63, wid = threadIdx.x >> 6;
  if (lane == 0) wsum[wid] = s;
  __syncthreads();
  if (threadIdx.x == 0) {
    float tot = (wsum[0] + wsum[1]) + (wsum[2] + wsum[3]);
    xbar[b] = tot * (1.0f / (float)HWPIX);
    __threadfence();  // publish xbar[b] before counting this block as done
    unsigned int old = atomicAdd(counter, 1u);
    is_last = (old == NMEANBLK - 1) ? 1 : 0;
  }
  __syncthreads();
  if (!is_last) return;

  // ---- tail block: all xbar is published; compute attp1 ----
  __threadfence();
  __shared__ float xb[NTOT][CDIM];   // 32 KB
  __shared__ float gap[NTOT][CR];    // 8 KB
  {
    volatile const float* vx = (volatile const float*)xbar;  // coherent reads
    for (int e = threadIdx.x; e < NTOT * CDIM; e += 256)
      xb[e >> 6][e & (CDIM - 1)] = vx[e];
  }
  __syncthreads();
  for (int e = threadIdx.x; e < NTOT * CR; e += 256) {
    const int nt = e >> 4, k = e & (CR - 1);
    const int t = nt & (TFR - 1), n0 = nt & ~(TFR - 1);
    float g = 0.f;
    if (t >= 1 && t <= TFR - 2) {
      for (int cc = 0; cc < CDIM; ++cc)
        g += sq_w[k * CDIM + cc] * (xb[n0][cc] - xb[nt][cc]);
    }
    gap[nt][k] = g;
  }
  __syncthreads();
  for (int e = threadIdx.x; e < NTOT * CDIM; e += 256) {
    const int nt = e >> 6, c = e & (CDIM - 1);
    float a = ex_b[c];
    #pragma unroll
    for (int k = 0; k < CR; ++k) a += ex_w[c * CR + k] * gap[nt][k];
    attp1[e] = 1.f + 1.f / (1.f + __expf(-a));
  }
}

// ---------------------------------------------------------------------------
// Kernel 2: fused main pass — EXACTLY R1's proven shape (3136 blocks, one
// float4 column of 8 frames per thread), with att folded into the shift
// weights so Sv[] is never materialized (8 live float4 instead of 16):
//   Sc[t] = sb + sw0*ap[t-1]*x[t-1] + sw1*ap[t]*x[t] + sw2*ap[t+1]*x[t+1]
//   Gc[t] = BN(gate-conv(x))        [BN folded into weights]
//   out   = Sc * sigmoid(Gc)
// ---------------------------------------------------------------------------
__global__ __launch_bounds__(256) void fused_shift_kernel(
    const float* __restrict__ x,
    const float* __restrict__ attp1,
    const float* __restrict__ shift_w, const float* __restrict__ shift_b,
    const float* __restrict__ gate_w,  const float* __restrict__ gate_b,
    const float* __restrict__ bn_gamma, const float* __restrict__ bn_beta,
    const float* __restrict__ bn_mean,  const float* __restrict__ bn_var,
    float* __restrict__ out) {
  const int tid = blockIdx.x * 256 + threadIdx.x;  // 0 .. 16*64*784-1
  const int q = tid % HW4;
  const int c = (tid / HW4) & (CDIM - 1);
  const int n = tid / (HW4 * CDIM);

  const float sw0 = shift_w[c * 3 + 0], sw1 = shift_w[c * 3 + 1],
              sw2 = shift_w[c * 3 + 2], sb = shift_b[c];
  const float inv = bn_gamma[c] * rsqrtf(bn_var[c] + 1e-3f);
  const float g0 = gate_w[c * 3 + 0] * inv, g1 = gate_w[c * 3 + 1] * inv,
              g2 = gate_w[c * 3 + 2] * inv;
  const float gbias = (gate_b[c] - bn_mean[c]) * inv + bn_beta[c];

  // attp1 padded with zeros at both ends: ap[t+1] = attp1(n, t, c)
  float ap[TFR + 2];
  ap[0] = 0.f;
  ap[TFR + 1] = 0.f;
  #pragma unroll
  for (int t = 0; t < TFR; ++t) ap[t + 1] = attp1[(n * TFR + t) * CDIM + c];

  const size_t base = ((size_t)(n * TFR) * CDIM + c) * HWPIX + (size_t)q * 4;
  const size_t tstride = (size_t)CDIM * HWPIX;  // frame stride in floats

  float4 xv[TFR];
  #pragma unroll
  for (int t = 0; t < TFR; ++t)
    xv[t] = *reinterpret_cast<const float4*>(x + base + (size_t)t * tstride);

  const float4 zero4 = make_float4(0.f, 0.f, 0.f, 0.f);
  #pragma unroll
  for (int t = 0; t < TFR; ++t) {
    const float e0 = sw0 * ap[t], e1 = sw1 * ap[t + 1], e2 = sw2 * ap[t + 2];
    const float4 xm = (t > 0) ? xv[t - 1] : zero4;
    const float4 xp = (t < TFR - 1) ? xv[t + 1] : zero4;
    float4 o;
    {
      const float sc = sb + e0 * xm.x + e1 * xv[t].x + e2 * xp.x;
      const float gc = gbias + g0 * xm.x + g1 * xv[t].x + g2 * xp.x;
      o.x = sc * (1.f / (1.f + __expf(-gc)));
    }
    {
      const float sc = sb + e0 * xm.y + e1 * xv[t].y + e2 * xp.y;
      const float gc = gbias + g0 * xm.y + g1 * xv[t].y + g2 * xp.y;
      o.y = sc * (1.f / (1.f + __expf(-gc)));
    }
    {
      const float sc = sb + e0 * xm.z + e1 * xv[t].z + e2 * xp.z;
      const float gc = gbias + g0 * xm.z + g1 * xv[t].z + g2 * xp.z;
      o.z = sc * (1.f / (1.f + __expf(-gc)));
    }
    {
      const float sc = sb + e0 * xm.w + e1 * xv[t].w + e2 * xp.w;
      const float gc = gbias + g0 * xm.w + g1 * xv[t].w + g2 * xp.w;
      o.w = sc * (1.f / (1.f + __expf(-gc)));
    }
    *reinterpret_cast<float4*>(out + base + (size_t)t * tstride) = o;
  }
}

extern "C" void kernel_launch(void* const* d_in, const int* in_sizes, int n_in,
                              void* d_out, int out_size, void* d_ws, size_t ws_size,
                              hipStream_t stream) {
  const float* x        = (const float*)d_in[0];
  const float* shift_w  = (const float*)d_in[1];
  const float* shift_b  = (const float*)d_in[2];
  const float* gate_w   = (const float*)d_in[3];
  const float* gate_b   = (const float*)d_in[4];
  const float* bn_gamma = (const float*)d_in[5];
  const float* bn_beta  = (const float*)d_in[6];
  const float* bn_mean  = (const float*)d_in[7];
  const float* bn_var   = (const float*)d_in[8];
  const float* sq_w     = (const float*)d_in[9];
  // d_in[10] = sq_b  (cancels in temporal diff -> unused)
  const float* ex_w     = (const float*)d_in[11];
  const float* ex_b     = (const float*)d_in[12];
  float* out = (float*)d_out;

  // ws layout: [counter (64 floats, aligned)] [xbar NT*C] [attp1 NT*C]
  unsigned int* counter = (unsigned int*)d_ws;
  float* xbar  = (float*)d_ws + 64;
  float* attp1 = (float*)d_ws + 64 + NTOT * CDIM;

  // zero the completion counter each launch (graph-capturable memset node)
  hipMemsetAsync(counter, 0, sizeof(unsigned int), stream);

  mean_att_kernel<<<NMEANBLK, 256, 0, stream>>>(x, sq_w, ex_w, ex_b,
                                                xbar, attp1, counter);
  fused_shift_kernel<<<(NBATCH * CDIM * HW4) / 256, 256, 0, stream>>>(
      x, attp1, shift_w, shift_b, gate_w, gate_b,
      bn_gamma, bn_beta, bn_mean, bn_var, out);
}

// Round 6
// 55.223 us; speedup vs baseline: 5.5394x; 5.5394x over previous
//
#include <hip/hip_runtime.h>
#include <math.h>

// Problem constants (from reference setup_inputs)
#define CDIM 64
#define CR 16
#define TFR 8
#define NBATCH 16      // NT / T
#define NTOT 128       // NT
#define HWPIX 3136     // 56*56
#define HW4 784        // HWPIX / 4

// ---------------------------------------------------------------------------
// Kernel 1 (R1-proven): per-(nt, c) spatial mean of x. grid = NT*C = 8192
// blocks x 256 threads; block b reduces x[b*3136 .. +3136).
// ---------------------------------------------------------------------------
__global__ __launch_bounds__(256) void spatial_mean_kernel(
    const float* __restrict__ x, float* __restrict__ xbar) {
  const int b = blockIdx.x;
  const float4* xp = reinterpret_cast<const float4*>(x + (size_t)b * HWPIX);
  float s = 0.f;
  for (int i = threadIdx.x; i < HW4; i += 256) {
    float4 v = xp[i];
    s += (v.x + v.y) + (v.z + v.w);
  }
  #pragma unroll
  for (int off = 32; off > 0; off >>= 1) s += __shfl_down(s, off, 64);
  __shared__ float wsum[4];
  const int lane = threadIdx.x & 63, wid = threadIdx.x >> 6;
  if (lane == 0) wsum[wid] = s;
  __syncthreads();
  if (threadIdx.x == 0) {
    float tot = (wsum[0] + wsum[1]) + (wsum[2] + wsum[3]);
    xbar[b] = tot * (1.0f / (float)HWPIX);
  }
}

// ---------------------------------------------------------------------------
// Kernel 2 (R1-proven, tiny): attp1 per (nt, c). grid = NT blocks x C threads.
// gap[k] = sum_c sq_w[k,c]*(xbar[n,0,c]-xbar[n,t,c])  (0 for t=T-1; sq_b cancels)
// attp1  = 1 + sigmoid(ex_w @ gap + ex_b)
// ---------------------------------------------------------------------------
__global__ __launch_bounds__(64) void att_kernel(
    const float* __restrict__ xbar,
    const float* __restrict__ sq_w,   // (CR, C) row-major
    const float* __restrict__ ex_w,   // (C, CR) row-major
    const float* __restrict__ ex_b,   // (C,)
    float* __restrict__ attp1) {
  const int nt = blockIdx.x;
  const int n = nt >> 3;
  const int t = nt & 7;
  const int c = threadIdx.x;
  __shared__ float d[CDIM];
  __shared__ float gap[CR];
  d[c] = (t == TFR - 1) ? 0.f
                        : (xbar[(n * TFR) * CDIM + c] - xbar[nt * CDIM + c]);
  __syncthreads();
  if (c < CR) {
    float g = 0.f;
    #pragma unroll
    for (int cc = 0; cc < CDIM; ++cc) g += sq_w[c * CDIM + cc] * d[cc];
    gap[c] = g;
  }
  __syncthreads();
  float a = ex_b[c];
  #pragma unroll
  for (int k = 0; k < CR; ++k) a += ex_w[c * CR + k] * gap[k];
  attp1[nt * CDIM + c] = 1.f + 1.f / (1.f + __expf(-a));
}

// ---------------------------------------------------------------------------
// Kernel 3: R1's proven shape (3136 blocks, one float4 column of 8 frames per
// thread) with att folded into the shift weights so Sv[] never materializes:
//   Sc[t] = sb + sw0*ap[t-1]*x[t-1] + sw1*ap[t]*x[t] + sw2*ap[t+1]*x[t+1]
//   Gc[t] = BN(gate-conv_T(x))   [BN folded into conv weights]
//   out   = Sc * sigmoid(Gc)
// 8 live float4 instead of 16 -> aim for <=64 VGPR (8 waves/SIMD band).
// ---------------------------------------------------------------------------
__global__ __launch_bounds__(256) void fused_shift_kernel(
    const float* __restrict__ x,
    const float* __restrict__ attp1,
    const float* __restrict__ shift_w, const float* __restrict__ shift_b,
    const float* __restrict__ gate_w,  const float* __restrict__ gate_b,
    const float* __restrict__ bn_gamma, const float* __restrict__ bn_beta,
    const float* __restrict__ bn_mean,  const float* __restrict__ bn_var,
    float* __restrict__ out) {
  const int tid = blockIdx.x * 256 + threadIdx.x;  // 0 .. 16*64*784-1
  const int q = tid % HW4;
  const int c = (tid / HW4) & (CDIM - 1);
  const int n = tid / (HW4 * CDIM);

  const float sw0 = shift_w[c * 3 + 0], sw1 = shift_w[c * 3 + 1],
              sw2 = shift_w[c * 3 + 2], sb = shift_b[c];
  const float inv = bn_gamma[c] * rsqrtf(bn_var[c] + 1e-3f);
  const float g0 = gate_w[c * 3 + 0] * inv, g1 = gate_w[c * 3 + 1] * inv,
              g2 = gate_w[c * 3 + 2] * inv;
  const float gbias = (gate_b[c] - bn_mean[c]) * inv + bn_beta[c];

  // ap[t+1] = attp1(n, t, c); zero-padded ends
  float ap[TFR + 2];
  ap[0] = 0.f;
  ap[TFR + 1] = 0.f;
  #pragma unroll
  for (int t = 0; t < TFR; ++t) ap[t + 1] = attp1[(n * TFR + t) * CDIM + c];

  const size_t base = ((size_t)(n * TFR) * CDIM + c) * HWPIX + (size_t)q * 4;
  const size_t tstride = (size_t)CDIM * HWPIX;  // frame stride in floats

  float4 xv[TFR];
  #pragma unroll
  for (int t = 0; t < TFR; ++t)
    xv[t] = *reinterpret_cast<const float4*>(x + base + (size_t)t * tstride);

  const float4 zero4 = make_float4(0.f, 0.f, 0.f, 0.f);
  #pragma unroll
  for (int t = 0; t < TFR; ++t) {
    const float e0 = sw0 * ap[t], e1 = sw1 * ap[t + 1], e2 = sw2 * ap[t + 2];
    const float4 xm = (t > 0) ? xv[t - 1] : zero4;
    const float4 xp = (t < TFR - 1) ? xv[t + 1] : zero4;
    float4 o;
    {
      const float sc = sb + e0 * xm.x + e1 * xv[t].x + e2 * xp.x;
      const float gc = gbias + g0 * xm.x + g1 * xv[t].x + g2 * xp.x;
      o.x = sc * (1.f / (1.f + __expf(-gc)));
    }
    {
      const float sc = sb + e0 * xm.y + e1 * xv[t].y + e2 * xp.y;
      const float gc = gbias + g0 * xm.y + g1 * xv[t].y + g2 * xp.y;
      o.y = sc * (1.f / (1.f + __expf(-gc)));
    }
    {
      const float sc = sb + e0 * xm.z + e1 * xv[t].z + e2 * xp.z;
      const float gc = gbias + g0 * xm.z + g1 * xv[t].z + g2 * xp.z;
      o.z = sc * (1.f / (1.f + __expf(-gc)));
    }
    {
      const float sc = sb + e0 * xm.w + e1 * xv[t].w + e2 * xp.w;
      const float gc = gbias + g0 * xm.w + g1 * xv[t].w + g2 * xp.w;
      o.w = sc * (1.f / (1.f + __expf(-gc)));
    }
    *reinterpret_cast<float4*>(out + base + (size_t)t * tstride) = o;
  }
}

extern "C" void kernel_launch(void* const* d_in, const int* in_sizes, int n_in,
                              void* d_out, int out_size, void* d_ws, size_t ws_size,
                              hipStream_t stream) {
  const float* x        = (const float*)d_in[0];
  const float* shift_w  = (const float*)d_in[1];
  const float* shift_b  = (const float*)d_in[2];
  const float* gate_w   = (const float*)d_in[3];
  const float* gate_b   = (const float*)d_in[4];
  const float* bn_gamma = (const float*)d_in[5];
  const float* bn_beta  = (const float*)d_in[6];
  const float* bn_mean  = (const float*)d_in[7];
  const float* bn_var   = (const float*)d_in[8];
  const float* sq_w     = (const float*)d_in[9];
  // d_in[10] = sq_b  (cancels in temporal diff -> unused)
  const float* ex_w     = (const float*)d_in[11];
  const float* ex_b     = (const float*)d_in[12];
  float* out = (float*)d_out;

  float* xbar  = (float*)d_ws;                 // NT*C floats
  float* attp1 = (float*)d_ws + NTOT * CDIM;   // NT*C floats

  spatial_mean_kernel<<<NTOT * CDIM, 256, 0, stream>>>(x, xbar);
  att_kernel<<<NTOT, CDIM, 0, stream>>>(xbar, sq_w, ex_w, ex_b, attp1);
  fused_shift_kernel<<<(NBATCH * CDIM * HW4) / 256, 256, 0, stream>>>(
      x, attp1, shift_w, shift_b, gate_w, gate_b,
      bn_gamma, bn_beta, bn_mean, bn_var, out);
}